// Round 10
// baseline (1017.749 us; speedup 1.0000x reference)
//
#include <hip/hip_runtime.h>
#include <math.h>

#define NUM_EMB 512
#define EMB_DIM 64
#define S_SPATIAL 32768   // 32*32*32
#define BATCH 4
#define NVEC (BATCH * S_SPATIAL)  // 131072 vectors
#define NCHUNK 4
#define KCHUNK (NUM_EMB / NCHUNK) // 128 codes per chunk

// Workspace layout (d_ws):
//   0      : double loss_accum
//   256    : float  cbnorm[512]            (ends 2304)
//   4096   : float  best[NCHUNK][NVEC]     (2 MB)
//   4096+2M: int    bk  [NCHUNK][NVEC]     (2 MB)
#define WS_BEST_OFF 4096
#define WS_BK_OFF   (4096 + NCHUNK * NVEC * 4)
#define WS_NEEDED   (4096 + 2 * NCHUNK * NVEC * 4)

// ---------------------------------------------------------------------------
__global__ void vq_prep(const float* __restrict__ cb,
                        float* __restrict__ cbnorm,
                        double* __restrict__ loss_accum) {
    int k = blockIdx.x * blockDim.x + threadIdx.x;
    if (k == 0) *loss_accum = 0.0;
    if (k < NUM_EMB) {
        const float* e = cb + k * EMB_DIM;
        float s = 0.f;
        #pragma unroll
        for (int c = 0; c < EMB_DIM; ++c)
            s = __fadd_rn(s, __fmul_rn(e[c], e[c]));
        cbnorm[k] = s;
    }
}

// ---------------------------------------------------------------------------
// Pass 1 (split-K, PAIR-SPLIT): 2 lanes per vector. Lane h in {0,1} keeps x
// components {4i+2h, 4i+2h+1} -> 32 resident floats/lane (~50 VGPR total),
// below the RA's ~64-reg occupancy budget, so the compiler cannot demote x
// to per-iteration reloads (R9's bottleneck: VGPR=56 < 64 needed -> 64
// VMEM reloads/iter -> VMEM-issue-bound, VALU capped at 67%).
// Codebook: per-lane float2 loads (2 distinct addrs/wave, L1/L2 broadcast).
// dot = fadd(fadd(a0,a1), fadd(a2,a3)) computed as fadd(s_self, s_other)
// after one shfl_xor -> BIT-IDENTICAL to the R2/R9-proven arithmetic.
// Grid = 1024 vector-groups x 4 chunks = 4096 blocks.
// ---------------------------------------------------------------------------
__global__ void vq_part(
        const float* __restrict__ in,
        const float* __restrict__ cb,
        const float* __restrict__ cbnorm,
        float* __restrict__ best,          // [NCHUNK][NVEC]
        int*   __restrict__ bk) {          // [NCHUNK][NVEC]
    const int tid   = threadIdx.x;
    const int h     = tid & 1;                 // component-half selector
    const int vg    = blockIdx.x & 1023;       // 1024 groups of 128 vectors
    const int chunk = blockIdx.x >> 10;
    const int n = vg * 128 + (tid >> 1);       // vector id
    const int b = n >> 15;
    const int s = n & (S_SPATIAL - 1);

    const float* xp = in + (size_t)b * EMB_DIM * S_SPATIAL + s;
    const size_t S = (size_t)S_SPATIAL;

    // ---- load all 64 comps (exact sequential xn chain), keep this lane's
    //      half: ka_i = x[4i+2h], kb_i = x[4i+2h+1] ----
    float xn = 0.f;
#define LDK(i)                                                              \
    float ka_##i, kb_##i;                                                   \
    {                                                                       \
        float c0 = xp[(4*i+0)*S], c1 = xp[(4*i+1)*S];                       \
        float c2 = xp[(4*i+2)*S], c3 = xp[(4*i+3)*S];                       \
        xn = __fadd_rn(xn, __fmul_rn(c0, c0));                              \
        xn = __fadd_rn(xn, __fmul_rn(c1, c1));                              \
        xn = __fadd_rn(xn, __fmul_rn(c2, c2));                              \
        xn = __fadd_rn(xn, __fmul_rn(c3, c3));                              \
        ka_##i = h ? c2 : c0;                                               \
        kb_##i = h ? c3 : c1;                                               \
    }
    LDK(0)  LDK(1)  LDK(2)  LDK(3)  LDK(4)  LDK(5)  LDK(6)  LDK(7)
    LDK(8)  LDK(9)  LDK(10) LDK(11) LDK(12) LDK(13) LDK(14) LDK(15)
#undef LDK

    const float* cbn = cbnorm + chunk * KCHUNK;
    // per-lane element pointer: row base + component offset 2h
    const float* ek = cb + (size_t)chunk * KCHUNK * EMB_DIM + 2 * h;

    float bestd = INFINITY;
    int bestk = 0;
    for (int k = 0; k < KCHUNK; ++k) {
        float aA = 0.f, aB = 0.f;   // = (a0,a1) for h=0, (a2,a3) for h=1
#define DOT(i) { const float2 e = *(const float2*)(ek + 4*i);               \
                 aA = fmaf(ka_##i, e.x, aA);                                \
                 aB = fmaf(kb_##i, e.y, aB); }
        DOT(0)  DOT(1)  DOT(2)  DOT(3)  DOT(4)  DOT(5)  DOT(6)  DOT(7)
        DOT(8)  DOT(9)  DOT(10) DOT(11) DOT(12) DOT(13) DOT(14) DOT(15)
#undef DOT
        float ss = __fadd_rn(aA, aB);          // fadd(a0,a1) or fadd(a2,a3)
        float so = __shfl_xor(ss, 1, 64);      // partner's half-sum
        float dot = __fadd_rn(ss, so);         // == fadd(fadd(a0,a1),fadd(a2,a3))
        float d = __fsub_rn(__fadd_rn(xn, cbn[k]),
                            __fmul_rn(2.f, dot));
        if (d < bestd) { bestd = d; bestk = k; }
        ek += EMB_DIM;
    }
    if (h == 0) {
        best[chunk * NVEC + n] = bestd;
        bk  [chunk * NVEC + n] = chunk * KCHUNK + bestk;
    }
}

// ---------------------------------------------------------------------------
// Pass 2: combine the 4 chunk-argmins (ascending chunk order + strict '<'
// == global first-index argmin), gather the winning code, write output,
// accumulate loss. c-tiled: thread = (vector, 16-channel tile) -> 2048 blocks.
// ---------------------------------------------------------------------------
__global__ __launch_bounds__(256) void vq_fin(
        const float* __restrict__ in,
        const float* __restrict__ cb,
        const float* __restrict__ best,
        const int*   __restrict__ bk,
        float* __restrict__ outq,
        double* __restrict__ loss_accum) {
    const int vg = blockIdx.x & 511;
    const int ct = blockIdx.x >> 9;          // channel tile: 16 channels
    const int n = vg * 256 + threadIdx.x;
    const int b = n >> 15;
    const int s = n & (S_SPATIAL - 1);

    float bd = best[n];
    int kk = bk[n];
    #pragma unroll
    for (int c = 1; c < NCHUNK; ++c) {
        float d = best[c * NVEC + n];
        if (d < bd) { bd = d; kk = bk[c * NVEC + n]; }
    }

    const size_t S = (size_t)S_SPATIAL;
    const float* xp = in + (size_t)b * EMB_DIM * S_SPATIAL + s + (size_t)(ct * 16) * S;
    float* op = outq + (size_t)b * EMB_DIM * S_SPATIAL + s + (size_t)(ct * 16) * S;
    const float4* q = (const float4*)(cb + (size_t)kk * EMB_DIM + ct * 16);

    float lsum = 0.f;
    #pragma unroll
    for (int i = 0; i < 4; ++i) {
        const float4 qv = q[i];
        float x0 = xp[(4*i+0)*S], x1 = xp[(4*i+1)*S];
        float x2 = xp[(4*i+2)*S], x3 = xp[(4*i+3)*S];
        op[(4*i+0)*S] = qv.x; op[(4*i+1)*S] = qv.y;
        op[(4*i+2)*S] = qv.z; op[(4*i+3)*S] = qv.w;
        float d0 = __fsub_rn(qv.x, x0);
        float d1 = __fsub_rn(qv.y, x1);
        float d2 = __fsub_rn(qv.z, x2);
        float d3 = __fsub_rn(qv.w, x3);
        lsum = __fadd_rn(lsum, __fmul_rn(d0, d0));
        lsum = __fadd_rn(lsum, __fmul_rn(d1, d1));
        lsum = __fadd_rn(lsum, __fmul_rn(d2, d2));
        lsum = __fadd_rn(lsum, __fmul_rn(d3, d3));
    }

    // wave reduce in double -> per-block atomic
    double ls = (double)lsum;
    #pragma unroll
    for (int off = 32; off > 0; off >>= 1)
        ls += __shfl_down(ls, off, 64);
    __shared__ double wsum[4];
    const int lane = threadIdx.x & 63;
    const int wid  = threadIdx.x >> 6;
    if (lane == 0) wsum[wid] = ls;
    __syncthreads();
    if (threadIdx.x == 0) {
        double t = ((wsum[0] + wsum[1]) + (wsum[2] + wsum[3]));
        atomicAdd(loss_accum, t);
    }
}

// ---------------------------------------------------------------------------
// Fallback single-kernel (R2 proven path) if ws is too small for partials.
// ---------------------------------------------------------------------------
__global__ __launch_bounds__(256, 2) void vq_main_single(
        const float* __restrict__ in,
        const float* __restrict__ cb,
        const float* __restrict__ cbnorm,
        float* __restrict__ outq,
        double* __restrict__ loss_accum) {
    const int n = blockIdx.x * 256 + threadIdx.x;
    const int b = n >> 15;
    const int s = n & (S_SPATIAL - 1);
    const float* xp = in + (size_t)b * EMB_DIM * S_SPATIAL + s;
    const size_t S = (size_t)S_SPATIAL;
#define LDX(i) const float4 x##i = make_float4(xp[(4*i+0)*S], xp[(4*i+1)*S], \
                                               xp[(4*i+2)*S], xp[(4*i+3)*S])
    LDX(0);  LDX(1);  LDX(2);  LDX(3);  LDX(4);  LDX(5);  LDX(6);  LDX(7);
    LDX(8);  LDX(9);  LDX(10); LDX(11); LDX(12); LDX(13); LDX(14); LDX(15);
#undef LDX
    float xn = 0.f;
#define XN(i) xn = __fadd_rn(xn, __fmul_rn(x##i.x, x##i.x)); \
              xn = __fadd_rn(xn, __fmul_rn(x##i.y, x##i.y)); \
              xn = __fadd_rn(xn, __fmul_rn(x##i.z, x##i.z)); \
              xn = __fadd_rn(xn, __fmul_rn(x##i.w, x##i.w))
    XN(0);  XN(1);  XN(2);  XN(3);  XN(4);  XN(5);  XN(6);  XN(7);
    XN(8);  XN(9);  XN(10); XN(11); XN(12); XN(13); XN(14); XN(15);
#undef XN
    float bestd = INFINITY;
    int bestk = 0;
    for (int k = 0; k < NUM_EMB; ++k) {
        const float4* ev = (const float4*)(cb + (size_t)k * EMB_DIM);
        float a0 = 0.f, a1 = 0.f, a2 = 0.f, a3 = 0.f;
#define DOT(i) { const float4 e = ev[i];            \
                 a0 = fmaf(x##i.x, e.x, a0);        \
                 a1 = fmaf(x##i.y, e.y, a1);        \
                 a2 = fmaf(x##i.z, e.z, a2);        \
                 a3 = fmaf(x##i.w, e.w, a3); }
        DOT(0);  DOT(1);  DOT(2);  DOT(3);  DOT(4);  DOT(5);  DOT(6);  DOT(7);
        DOT(8);  DOT(9);  DOT(10); DOT(11); DOT(12); DOT(13); DOT(14); DOT(15);
#undef DOT
        float dot = __fadd_rn(__fadd_rn(a0, a1), __fadd_rn(a2, a3));
        float d = __fsub_rn(__fadd_rn(xn, cbnorm[k]),
                            __fmul_rn(2.f, dot));
        if (d < bestd) { bestd = d; bestk = k; }
    }
    const float4* q = (const float4*)(cb + (size_t)bestk * EMB_DIM);
    float* op = outq + (size_t)b * EMB_DIM * S_SPATIAL + s;
    float lsum = 0.f;
#define OUTC(i) { const float4 qv = q[i];                                   \
                  op[(4*i+0)*S] = qv.x; op[(4*i+1)*S] = qv.y;               \
                  op[(4*i+2)*S] = qv.z; op[(4*i+3)*S] = qv.w;               \
                  float d0 = __fsub_rn(qv.x, x##i.x);                       \
                  float d1 = __fsub_rn(qv.y, x##i.y);                       \
                  float d2 = __fsub_rn(qv.z, x##i.z);                       \
                  float d3 = __fsub_rn(qv.w, x##i.w);                       \
                  lsum = __fadd_rn(lsum, __fmul_rn(d0, d0));                \
                  lsum = __fadd_rn(lsum, __fmul_rn(d1, d1));                \
                  lsum = __fadd_rn(lsum, __fmul_rn(d2, d2));                \
                  lsum = __fadd_rn(lsum, __fmul_rn(d3, d3)); }
    OUTC(0);  OUTC(1);  OUTC(2);  OUTC(3);  OUTC(4);  OUTC(5);  OUTC(6);  OUTC(7);
    OUTC(8);  OUTC(9);  OUTC(10); OUTC(11); OUTC(12); OUTC(13); OUTC(14); OUTC(15);
#undef OUTC
    double ls = (double)lsum;
    #pragma unroll
    for (int off = 32; off > 0; off >>= 1)
        ls += __shfl_down(ls, off, 64);
    __shared__ double wsum[4];
    const int lane = threadIdx.x & 63;
    const int wid  = threadIdx.x >> 6;
    if (lane == 0) wsum[wid] = ls;
    __syncthreads();
    if (threadIdx.x == 0)
        atomicAdd(loss_accum, (wsum[0] + wsum[1]) + (wsum[2] + wsum[3]));
}

// ---------------------------------------------------------------------------
__global__ void vq_final(const double* __restrict__ loss_accum,
                         float* __restrict__ out0) {
    double m = *loss_accum / (double)((long long)NVEC * EMB_DIM);
    float mf = (float)m;
    out0[0] = __fadd_rn(mf, __fmul_rn(0.25f, mf));
}

extern "C" void kernel_launch(void* const* d_in, const int* in_sizes, int n_in,
                              void* d_out, int out_size, void* d_ws, size_t ws_size,
                              hipStream_t stream) {
    const float* in = (const float*)d_in[0];   // [4, 64, 32, 32, 32]
    const float* cb = (const float*)d_in[1];   // [512, 64]
    float* out = (float*)d_out;                // [0]=loss, [1..]=quantized

    double* loss_accum = (double*)d_ws;
    float* cbnorm = (float*)((char*)d_ws + 256);

    vq_prep<<<4, 128, 0, stream>>>(cb, cbnorm, loss_accum);

    if (ws_size >= (size_t)WS_NEEDED) {
        float* best = (float*)((char*)d_ws + WS_BEST_OFF);
        int*   bkp  = (int*)  ((char*)d_ws + WS_BK_OFF);
        vq_part<<<1024 * NCHUNK, 256, 0, stream>>>(in, cb, cbnorm, best, bkp);
        vq_fin <<<512 * 4,       256, 0, stream>>>(in, cb, best, bkp, out + 1,
                                                   loss_accum);
    } else {
        vq_main_single<<<NVEC / 256, 256, 0, stream>>>(in, cb, cbnorm, out + 1,
                                                       loss_accum);
    }
    vq_final<<<1, 1, 0, stream>>>(loss_accum, out);
}

// Round 12
// 312.482 us; speedup vs baseline: 3.2570x; 3.2570x over previous
//
#include <hip/hip_runtime.h>
#include <math.h>

#define NUM_EMB 512
#define EMB_DIM 64
#define S_SPATIAL 32768   // 32*32*32
#define BATCH 4
#define NVEC (BATCH * S_SPATIAL)  // 131072 vectors
#define KTILE 8
#define NTILE (NUM_EMB / KTILE)   // 64 tiles of 8 codes

// Workspace layout (d_ws):
//   0   : double loss_accum
//   256 : float  cbnorm[512]

// ---------------------------------------------------------------------------
__global__ void vq_prep(const float* __restrict__ cb,
                        float* __restrict__ cbnorm,
                        double* __restrict__ loss_accum) {
    int k = blockIdx.x * blockDim.x + threadIdx.x;
    if (k == 0) *loss_accum = 0.0;
    if (k < NUM_EMB) {
        const float* e = cb + k * EMB_DIM;
        float s = 0.f;
        #pragma unroll
        for (int c = 0; c < EMB_DIM; ++c)
            s = __fadd_rn(s, __fmul_rn(e[c], e[c]));
        cbnorm[k] = s;
    }
}

// ---------------------------------------------------------------------------
// Block = 256 vectors. x tile staged in LDS as [comp][vec] (64KB, conflict-
// free both sides: lanes hit consecutive banks). K-loop re-blocked into 64
// tiles of 8 codes: per c-step = 1 ds_read_b32 + 8 v_fmac with wave-uniform
// codebook values (s_loads). This removes the per-k x reloads that made
// R2/R9 VMEM-issue-bound (compiler refuses 64 resident VGPRs for x: R2=56,
// R7=48, R9=56, R10=32 across four attempts). 8 independent accumulators
// give full FMA ILP. Tile loop is in-thread -> global argmin, no partials.
// d-formula / xn chain / loss chain / strict-'<' ascending-k tie-break are
// identical to the R2-proven kernel; dot is one sequential fmaf chain
// (error ~1e-8 vs the proven 4-split, far below empirical argmin gaps).
// ---------------------------------------------------------------------------
__global__ __launch_bounds__(256) void vq_main(
        const float* __restrict__ in,
        const float* __restrict__ cb,
        const float* __restrict__ cbnorm,
        float* __restrict__ outq,          // d_out + 1 (quantized, [B,C,D,H,W])
        double* __restrict__ loss_accum) {
    __shared__ float ldsx[EMB_DIM * 256];  // [comp][vec], 64 KB

    const int tid = threadIdx.x;
    const int n = blockIdx.x * 256 + tid;  // this thread's vector id
    const int b = n >> 15;                 // n / S_SPATIAL
    const int s0 = (blockIdx.x * 256) & (S_SPATIAL - 1);  // block's spatial base
    const size_t S = (size_t)S_SPATIAL;

    const float* xp = in + (size_t)b * EMB_DIM * S_SPATIAL + s0;

    // ---- stage x tile into LDS; accumulate xn (sequential c order, same
    //      chain as the proven kernel) for this thread's own vector ----
    float xn = 0.f;
    #pragma unroll
    for (int c = 0; c < EMB_DIM; ++c) {
        float v = xp[(size_t)c * S + tid];       // coalesced
        ldsx[c * 256 + tid] = v;                 // conflict-free write
        xn = __fadd_rn(xn, __fmul_rn(v, v));
    }
    __syncthreads();

    // ---- argmin over 512 codes, 64 tiles x 8 codes ----
    float best = INFINITY;
    int bestk = 0;
    for (int t = 0; t < NTILE; ++t) {
        const float* E = cb + (size_t)t * KTILE * EMB_DIM;  // uniform -> s_load
        const float* cbn = cbnorm + t * KTILE;

        float a[KTILE];
        #pragma unroll
        for (int j = 0; j < KTILE; ++j) a[j] = 0.f;

        #pragma unroll 8
        for (int c = 0; c < EMB_DIM; ++c) {
            float xc = ldsx[c * 256 + tid];      // 1 ds_read_b32, 2-way free
            #pragma unroll
            for (int j = 0; j < KTILE; ++j)
                a[j] = fmaf(xc, E[j * EMB_DIM + c], a[j]);  // VGPR x SGPR
        }

        #pragma unroll
        for (int j = 0; j < KTILE; ++j) {
            float d = __fsub_rn(__fadd_rn(xn, cbn[j]),
                                __fmul_rn(2.f, a[j]));
            if (d < best) { best = d; bestk = t * KTILE + j; }
        }
    }

    // ---- gather winning code, write output, loss partial ----
    const float4* q = (const float4*)(cb + (size_t)bestk * EMB_DIM);
    float* op = outq + (size_t)b * EMB_DIM * S_SPATIAL + s0 + tid;
    float lsum = 0.f;
    #pragma unroll
    for (int i = 0; i < EMB_DIM / 4; ++i) {
        const float4 qv = q[i];                  // per-lane gather, L2-hot
        float x0 = ldsx[(4*i+0) * 256 + tid];
        float x1 = ldsx[(4*i+1) * 256 + tid];
        float x2 = ldsx[(4*i+2) * 256 + tid];
        float x3 = ldsx[(4*i+3) * 256 + tid];
        op[(size_t)(4*i+0) * S] = qv.x;
        op[(size_t)(4*i+1) * S] = qv.y;
        op[(size_t)(4*i+2) * S] = qv.z;
        op[(size_t)(4*i+3) * S] = qv.w;
        float d0 = __fsub_rn(qv.x, x0);
        float d1 = __fsub_rn(qv.y, x1);
        float d2 = __fsub_rn(qv.z, x2);
        float d3 = __fsub_rn(qv.w, x3);
        lsum = __fadd_rn(lsum, __fmul_rn(d0, d0));
        lsum = __fadd_rn(lsum, __fmul_rn(d1, d1));
        lsum = __fadd_rn(lsum, __fmul_rn(d2, d2));
        lsum = __fadd_rn(lsum, __fmul_rn(d3, d3));
    }

    // ---- block reduction of lsum -> one double atomicAdd per block ----
    double ls = (double)lsum;
    #pragma unroll
    for (int off = 32; off > 0; off >>= 1)
        ls += __shfl_down(ls, off, 64);
    __shared__ double wsum[4];
    const int lane = tid & 63;
    const int wid  = tid >> 6;
    if (lane == 0) wsum[wid] = ls;
    __syncthreads();
    if (tid == 0) {
        double tsum = ((wsum[0] + wsum[1]) + (wsum[2] + wsum[3]));
        atomicAdd(loss_accum, tsum);
    }
}

// ---------------------------------------------------------------------------
__global__ void vq_final(const double* __restrict__ loss_accum,
                         float* __restrict__ out0) {
    double m = *loss_accum / (double)((long long)NVEC * EMB_DIM);
    float mf = (float)m;
    out0[0] = __fadd_rn(mf, __fmul_rn(0.25f, mf));
}

extern "C" void kernel_launch(void* const* d_in, const int* in_sizes, int n_in,
                              void* d_out, int out_size, void* d_ws, size_t ws_size,
                              hipStream_t stream) {
    const float* in = (const float*)d_in[0];   // [4, 64, 32, 32, 32]
    const float* cb = (const float*)d_in[1];   // [512, 64]
    float* out = (float*)d_out;                // [0]=loss, [1..]=quantized

    double* loss_accum = (double*)d_ws;
    float* cbnorm = (float*)((char*)d_ws + 256);

    vq_prep<<<4, 128, 0, stream>>>(cb, cbnorm, loss_accum);
    vq_main<<<NVEC / 256, 256, 0, stream>>>(in, cb, cbnorm, out + 1, loss_accum);
    vq_final<<<1, 1, 0, stream>>>(loss_accum, out);
}